// Round 7
// baseline (444.588 us; speedup 1.0000x reference)
//
#include <hip/hip_runtime.h>
#include <stdint.h>

#define B_ 8
#define D_ 512
#define N_ 16384
#define K_ 32
#define XS 44   // X-tile row stride (u16): 22 words/row -> Dn=8 rows shift banks by 16 (conflict-free MFMA gathers)
#define LS 36   // lgp [k][n] row stride (u16): 18 words -> lanes 0..7 start banks {0,18,4,22,8,26,12,30}, all distinct
#define AS 40   // A_lds row stride (u16): 80 B -> 16B-aligned b128 A-op reads, starts {0,20,8,28,...} distinct

typedef __attribute__((ext_vector_type(8))) short short8;
typedef __attribute__((ext_vector_type(16))) float f32x16;

union F8 { short8 v; unsigned short s[8]; uint32_t u[4]; uint4 q; };

__device__ __forceinline__ uint32_t bfpack2(float lo, float hi) {
    uint32_t a = __float_as_uint(lo);
    uint32_t b = __float_as_uint(hi);
    a += 0x7FFFu + ((a >> 16) & 1u);
    b += 0x7FFFu + ((b >> 16) & 1u);
    return (a >> 16) | (b & 0xFFFF0000u);
}
__device__ __forceinline__ unsigned short bf16of(float x) {
    uint32_t a = __float_as_uint(x);
    a += 0x7FFFu + ((a >> 16) & 1u);
    return (unsigned short)(a >> 16);
}
__device__ __forceinline__ float bf16tof(unsigned short u) {
    return __uint_as_float(((uint32_t)u) << 16);
}
__device__ __forceinline__ float bflo(uint32_t v) { return __uint_as_float(v << 16); }
__device__ __forceinline__ float bfhi(uint32_t v) { return __uint_as_float(v & 0xFFFF0000u); }

// LDS-only barrier (no vmcnt drain)
__device__ __forceinline__ void bar_lds() {
    __builtin_amdgcn_s_waitcnt(0xC07F);  // vmcnt=max, expcnt=7, lgkmcnt=0
    __builtin_amdgcn_s_barrier();
}

// 512 threads = 8 waves; 2 blocks/CU (~70 KB LDS, <=128 VGPR).
// Per block: 256 n (8 tiles of 32) x 512 d; d split 8 ways across waves.
__launch_bounds__(512, 4)
__global__ void encode_kernel(const float* __restrict__ X,
                              const float* __restrict__ Cg,
                              const float* __restrict__ scale,
                              unsigned short* __restrict__ part,
                              float* __restrict__ aSumPart)
{
    __shared__ unsigned short xsT[D_ * XS];      // 45056 B: X^T tile bf16 [d][n]
    __shared__ unsigned short lgpS[8 * 32 * LS]; // 18432 B: GEMM1 d-partials bf16 [w][k][n]
    __shared__ unsigned short A_lds[K_ * AS];    //  2560 B: A bf16 [k][n]
    __shared__ float    x2p[8][32];              //  1024 B: per-wave x2 partials
    __shared__ float    scs[K_], c2s[K_];
    __shared__ float    c2tmp[K_][17];           //  2176 B
    __shared__ float    aSumLds[K_];

    const int tid = threadIdx.x;
    const int l   = tid & 63;
    const int w   = __builtin_amdgcn_readfirstlane(tid >> 6);  // wave 0..7
    const int lc  = l & 31;   // MFMA row/col lane
    const int nh  = l >> 5;   // MFMA k-dim half
    const int b     = blockIdx.x >> 6;
    const int chunk = blockIdx.x & 63;     // 64 chunks of 256 n per batch

    // ---- pre-loop: scale + ||c_k||^2 (fp32), zero aSumLds ----
    {
        int k = tid >> 4, dg = tid & 15;
        const float* cr = Cg + k * D_ + dg * 32;
        float s2 = 0.f;
#pragma unroll
        for (int i = 0; i < 8; ++i) {
            float4 v = *(const float4*)(cr + i * 4);
            s2 += v.x * v.x + v.y * v.y + v.z * v.z + v.w * v.w;
        }
        c2tmp[k][dg] = s2;
        if (tid < K_) { scs[tid] = scale[tid]; aSumLds[tid] = 0.f; }
    }
    __syncthreads();
    if (tid < K_) {
        float s = 0.f;
#pragma unroll
        for (int dg = 0; dg < 16; ++dg) s += c2tmp[tid][dg];
        c2s[tid] = s;
    }

    // ---- preload C fragments (GEMM1 B-op): wave w owns d in [64w, 64w+64) ----
    F8 cfr[4];
#pragma unroll
    for (int ss = 0; ss < 4; ++ss) {
        int d0 = 64 * w + ss * 16 + nh * 8;
        const float* cp = Cg + lc * D_ + d0;
        float4 a  = *(const float4*)(cp);
        float4 bq = *(const float4*)(cp + 4);
        cfr[ss].u[0] = bfpack2(a.x, a.y);
        cfr[ss].u[1] = bfpack2(a.z, a.w);
        cfr[ss].u[2] = bfpack2(bq.x, bq.y);
        cfr[ss].u[3] = bfpack2(bq.z, bq.w);
    }

    f32x16 eacc[2];
#pragma unroll
    for (int ti = 0; ti < 2; ++ti)
#pragma unroll
        for (int r = 0; r < 16; ++r) eacc[ti][r] = 0.f;
    float aSumReg = 0.f;

    // softmax lane map (waves 0..3): lane = k (lc), nh picks n-quad; wave w -> n in [8w, 8w+8)
    const int n0s = 8 * (w & 3) + 4 * nh;

    const int dl = tid >> 3;  // staging d-line 0..63 (d = dl + 64r)
    const int nq = tid & 7;   // staging n-quad
    const size_t xbase = (size_t)b * D_ * N_ + (size_t)chunk * 256;

    for (int t = 0; t < 8; ++t) {
        bar_lds();  // B0: previous tile's GEMM2 done -> xsT reusable

        // ---- stage: global fp32 [d][n] -> bf16 LDS + per-wave x2 ----
        {
            const float* Xp = X + xbase + t * 32 + nq * 4;
            float4 x2a; x2a.x = x2a.y = x2a.z = x2a.w = 0.f;
#pragma unroll
            for (int r = 0; r < 8; ++r) {
                int d = dl + 64 * r;
                float4 v = *(const float4*)(Xp + (size_t)d * N_);
                x2a.x += v.x * v.x; x2a.y += v.y * v.y;
                x2a.z += v.z * v.z; x2a.w += v.w * v.w;
                uint2 p;
                p.x = bfpack2(v.x, v.y);
                p.y = bfpack2(v.z, v.w);
                *(uint2*)&xsT[d * XS + nq * 4] = p;
            }
#pragma unroll
            for (int m = 8; m <= 32; m <<= 1) {
                x2a.x += __shfl_xor(x2a.x, m);
                x2a.y += __shfl_xor(x2a.y, m);
                x2a.z += __shfl_xor(x2a.z, m);
                x2a.w += __shfl_xor(x2a.w, m);
            }
            if (l < 8) *(float4*)&x2p[w][nq * 4] = x2a;
        }

        bar_lds();  // B1: tile + x2 partials visible

        // ---- GEMM1: logits d-partials, wave w covers d in [64w, 64w+64) ----
        {
            f32x16 lacc;
#pragma unroll
            for (int r = 0; r < 16; ++r) lacc[r] = 0.f;
#pragma unroll
            for (int ss = 0; ss < 4; ++ss) {
                int d0 = 64 * w + ss * 16 + nh * 8;
                F8 af;
#pragma unroll
                for (int j = 0; j < 8; ++j)
                    af.s[j] = xsT[(d0 + j) * XS + lc];
                lacc = __builtin_amdgcn_mfma_f32_32x32x16_bf16(af.v, cfr[ss].v, lacc, 0, 0, 0);
            }
            // D: col=lc (=k), row = (r&3)+8*(r>>2)+4*nh (=n).
            // Groups g=r>>2 are 4 consecutive n at n0 = 8g+4nh -> b64 writes to [k][n].
#pragma unroll
            for (int g = 0; g < 4; ++g) {
                int n0 = 8 * g + 4 * nh;
                uint2 pv;
                pv.x = bfpack2(lacc[4 * g],     lacc[4 * g + 1]);
                pv.y = bfpack2(lacc[4 * g + 2], lacc[4 * g + 3]);
                *(uint2*)&lgpS[(w * 32 + lc) * LS + n0] = pv;
            }
        }

        bar_lds();  // B2: all d-partials + x2 ready

        // ---- softmax (waves 0..3): lane = k, 4 n per lane ----
        if (w < 4) {
            float xc0 = 0.f, xc1 = 0.f, xc2 = 0.f, xc3 = 0.f;
            float4 x2v; x2v.x = x2v.y = x2v.z = x2v.w = 0.f;
#pragma unroll
            for (int wp = 0; wp < 8; ++wp) {
                uint2 pv = *(const uint2*)&lgpS[(wp * 32 + lc) * LS + n0s];
                xc0 += bflo(pv.x); xc1 += bfhi(pv.x);
                xc2 += bflo(pv.y); xc3 += bfhi(pv.y);
                float4 xv = *(const float4*)&x2p[wp][n0s];
                x2v.x += xv.x; x2v.y += xv.y; x2v.z += xv.z; x2v.w += xv.w;
            }
            float sck = scs[lc], c2k = c2s[lc];
            float s0 = sck * (x2v.x - 2.f * xc0 + c2k);
            float s1 = sck * (x2v.y - 2.f * xc1 + c2k);
            float s2 = sck * (x2v.z - 2.f * xc2 + c2k);
            float s3 = sck * (x2v.w - 2.f * xc3 + c2k);
            float m0 = s0, m1 = s1, m2 = s2, m3 = s3;
#pragma unroll
            for (int mk = 1; mk <= 16; mk <<= 1) {
                m0 = fmaxf(m0, __shfl_xor(m0, mk));
                m1 = fmaxf(m1, __shfl_xor(m1, mk));
                m2 = fmaxf(m2, __shfl_xor(m2, mk));
                m3 = fmaxf(m3, __shfl_xor(m3, mk));
            }
            float e0 = __expf(s0 - m0), e1 = __expf(s1 - m1);
            float e2 = __expf(s2 - m2), e3 = __expf(s3 - m3);
            float t0 = e0, t1 = e1, t2 = e2, t3 = e3;
#pragma unroll
            for (int mk = 1; mk <= 16; mk <<= 1) {
                t0 += __shfl_xor(t0, mk);
                t1 += __shfl_xor(t1, mk);
                t2 += __shfl_xor(t2, mk);
                t3 += __shfl_xor(t3, mk);
            }
            e0 /= t0; e1 /= t1; e2 /= t2; e3 /= t3;
            aSumReg += e0 + e1 + e2 + e3;
            uint2 av;
            av.x = bfpack2(e0, e1);
            av.y = bfpack2(e2, e3);
            *(uint2*)&A_lds[lc * AS + n0s] = av;
        }

        bar_lds();  // B3: A ready

        // ---- GEMM2: E[k][d] += A[k][n] * X[n][d], wave w d-block [64w, 64w+64) ----
#pragma unroll
        for (int ti = 0; ti < 2; ++ti) {
            int dcol = 64 * w + 32 * ti + lc;
#pragma unroll
            for (int ns = 0; ns < 2; ++ns) {
                F8 af, bf;
                af.q = *(const uint4*)&A_lds[lc * AS + ns * 16 + nh * 8];
                uint2 b0 = *(const uint2*)&xsT[dcol * XS + ns * 16 + nh * 8];
                uint2 b1 = *(const uint2*)&xsT[dcol * XS + ns * 16 + nh * 8 + 4];
                bf.u[0] = b0.x; bf.u[1] = b0.y; bf.u[2] = b1.x; bf.u[3] = b1.y;
                eacc[ti] = __builtin_amdgcn_mfma_f32_32x32x16_bf16(af.v, bf.v, eacc[ti], 0, 0, 0);
            }
        }
    }

    // ---- finalize: per-block bf16 partial stores (nontemporal, no atomics) ----
    unsigned short* pB = part + (size_t)blockIdx.x * (K_ * D_);
#pragma unroll
    for (int ti = 0; ti < 2; ++ti) {
        int d = 64 * w + 32 * ti + lc;
#pragma unroll
        for (int r = 0; r < 16; ++r) {
            int k = (r & 3) + 8 * (r >> 2) + 4 * nh;
            __builtin_nontemporal_store(bf16of(eacc[ti][r]), &pB[k * D_ + d]);
        }
    }

    // aSum: lane holds sum over its n for k=lc; fold nh halves, tiny LDS atomics
    if (w < 4) {
        aSumReg += __shfl_xor(aSumReg, 32);
        if (l < 32) unsafeAtomicAdd(&aSumLds[lc], aSumReg);
    }
    __syncthreads();
    if (tid < K_) aSumPart[blockIdx.x * K_ + tid] = aSumLds[tid];
}

// One block per (b,k,d-half): out[b,k,d] = sum_c part[..] - aSum[b,k]*C[k,d]
__launch_bounds__(256)
__global__ void finish_kernel(const unsigned short* __restrict__ part,
                              const float* __restrict__ aSumPart,
                              const float* __restrict__ Cg,
                              float* __restrict__ out)
{
    __shared__ float sA;
    const int bk = blockIdx.x >> 1;
    const int b  = bk >> 5;
    const int k  = bk & 31;
    const int d  = (blockIdx.x & 1) * 256 + threadIdx.x;

    if (threadIdx.x < 64) {
        float v = aSumPart[(size_t)((b << 6) + threadIdx.x) * K_ + k];
#pragma unroll
        for (int m = 1; m <= 32; m <<= 1) v += __shfl_xor(v, m);
        if (threadIdx.x == 0) sA = v;
    }
    __syncthreads();

    const unsigned short* p = part + ((size_t)(b * 64) * K_ + k) * D_ + d;
    float s = 0.f;
#pragma unroll 8
    for (int c = 0; c < 64; ++c)
        s += bf16tof(__builtin_nontemporal_load(&p[(size_t)c * (K_ * D_)]));
    out[(size_t)bk * D_ + d] = s - sA * Cg[k * D_ + d];
}

extern "C" void kernel_launch(void* const* d_in, const int* in_sizes, int n_in,
                              void* d_out, int out_size, void* d_ws, size_t ws_size,
                              hipStream_t stream)
{
    const float* X  = (const float*)d_in[0];
    const float* C  = (const float*)d_in[1];
    const float* sc = (const float*)d_in[2];
    float* out = (float*)d_out;

    unsigned short* part = (unsigned short*)d_ws;              // 512*K*D bf16 (16 MB)
    float* aSumPart = (float*)(part + (size_t)512 * K_ * D_);  // 512*K fp32

    encode_kernel<<<B_ * 64, 512, 0, stream>>>(X, C, sc, part, aSumPart);
    finish_kernel<<<B_ * K_ * 2, 256, 0, stream>>>(part, aSumPart, C, out);
}